// Round 5
// baseline (265.515 us; speedup 1.0000x reference)
//
#include <hip/hip_runtime.h>
#include <hip/hip_fp16.h>
#include <float.h>

#define DIMD   128
#define KCODES 1024
#define NROWS  65536
#define TAU    0.032f
#define SEG_R  16    // rows per segsum group

typedef __attribute__((ext_vector_type(8)))  _Float16 half8;
typedef __attribute__((ext_vector_type(16))) float f32x16;

union U8 { uint4 u; half8 h; };

__device__ __forceinline__ unsigned packh2(float a, float b) {
    __half2 t = __floats2half2_rn(a, b);
    return *(unsigned*)&t;
}

// ---- fused: preconvert codebook (-2*e) f16 (blocks 0..63) + enorm (64..67) + zero counts (68)
// ehg holds f16(-2*embed): folds the "-2*dot" scale into the MFMA so the distance is
// acc_init(ee) + x·(-2e) with no per-element fmaf in the hot loop.
__global__ __launch_bounds__(256) void pre_kernel(
    const float* __restrict__ embed, uint4* __restrict__ ehg,
    float* __restrict__ enorm, uint4* __restrict__ zero_region)
{
    if (blockIdx.x < 64) {
        int t = blockIdx.x * 256 + threadIdx.x;     // 0..16383
        int chunk = t >> 9;
        int s = (t >> 6) & 7;
        int L = t & 63;
        const float* src = embed + ((size_t)(chunk * 32 + (L & 31)) * DIMD) + s * 16 + (L >> 5) * 8;
        float4 a = *(const float4*)src;
        float4 b = *(const float4*)(src + 4);
        float f[8] = {a.x, a.y, a.z, a.w, b.x, b.y, b.z, b.w};
        uint4 H;
        unsigned* hw = (unsigned*)&H;
#pragma unroll
        for (int j = 0; j < 4; ++j) hw[j] = packh2(-2.f * f[2 * j], -2.f * f[2 * j + 1]);
        ehg[t] = H;
    } else if (blockIdx.x < 68) {
        int k = (blockIdx.x - 64) * 256 + threadIdx.x;
        const float4* e = (const float4*)(embed + (size_t)k * DIMD);
        float s = 0.f;
#pragma unroll
        for (int c = 0; c < DIMD / 4; ++c) {
            float4 v = e[c];
            s += v.x * v.x + v.y * v.y + v.z * v.z + v.w * v.w;
        }
        enorm[k] = s;
    } else {
        uint4 z = {0, 0, 0, 0};
        zero_region[threadIdx.x] = z;
        zero_region[threadIdx.x + 256] = z;
    }
}

// ---------------- fused MFMA distance + argmin (top-2) ----------------
// STRUCTURE = round-0 verbatim (58.6 µs): single-buffer Bs[512], two __syncthreads per
// chunk, plain reg-staged copy, per-k-step bh read. Structural post-mortems:
//  - R1/R4 (global_load_lds double-buffer, either stage/read order): identical 77-79 µs,
//    WRITE 8.2 MB spill signature from +32 VGPR batched bh[8] at the 128-reg cap.
//    Source-level pipelining loses to implicit multi-wave overlap (guide CM#5). DO NOT
//    re-pipeline this loop.
//  - R3 (K-split, 4 blocks/CU): occupancy stayed ~20%, staging doubled -> 74 µs.
//  - R2: launch_bounds(256,4) -> 1.5 GB scratch. Keep (256,2).
// VALU wins kept (R1-verified, -4.5 µs VALU busy): packed-int top-2
// ((bits(d) & ~31) | chunk; code low 5 bits = lane n; trunc err <= ~0.001 << TAU,
// recheck repairs), -2e-folded codebook, acc init = ee (no per-elem fmaf), Es in LDS.
__global__ __launch_bounds__(256, 2) void argmin_mfma(
    const float* __restrict__ x, const uint4* __restrict__ ehg,
    const float* __restrict__ enorm,
    int* __restrict__ ind_i, float* __restrict__ ind_f,
    int* __restrict__ wl, int* __restrict__ wl_cnt)
{
    __shared__ uint4 Bs[512];      // one chunk of eh f16 frags (8 KB)
    __shared__ float Es[KCODES];   // all code norms (4 KB)

    const int tid  = threadIdx.x;
    const int wave = tid >> 6;
    const int lane = tid & 63;
    const int n    = lane & 31;
    const int h    = lane >> 5;
    const int row0 = blockIdx.x * 128;
    const int rowA = row0 + wave * 32 + n;

    ((float4*)Es)[tid] = ((const float4*)enorm)[tid];   // visible after first barrier

    // A fragments: x split into f16 hi/lo, held in regs for all 8 k-steps
    half8 xh[8], xl[8];
    const float* xrow = x + (size_t)rowA * DIMD + h * 8;
#pragma unroll
    for (int s = 0; s < 8; ++s) {
        float4 a = *(const float4*)(xrow + s * 16);
        float4 b = *(const float4*)(xrow + s * 16 + 4);
        float f[8] = {a.x, a.y, a.z, a.w, b.x, b.y, b.z, b.w};
        U8 th, tl;
        unsigned* ph = (unsigned*)&th.u;
        unsigned* pl = (unsigned*)&tl.u;
#pragma unroll
        for (int j = 0; j < 4; ++j) {
            float u0 = f[2 * j], u1 = f[2 * j + 1];
            __half2 hh = __floats2half2_rn(u0, u1);
            ph[j] = *(unsigned*)&hh;
            float2 back = __half22float2(hh);
            __half2 ll = __floats2half2_rn(u0 - back.x, u1 - back.y);
            pl[j] = *(unsigned*)&ll;
        }
        xh[s] = th.h; xl[s] = tl.h;
    }

    int bestv[16], best2[16];
#pragma unroll
    for (int r = 0; r < 16; ++r) { bestv[r] = 0x7FFFFFFF; best2[r] = 0x7FFFFFFF; }

    for (int c = 0; c < KCODES / 32; ++c) {
        __syncthreads();   // previous chunk's Bs reads done
        {
            const uint4* sh = ehg + (size_t)c * 512;
            Bs[tid]       = sh[tid];
            Bs[tid + 256] = sh[tid + 256];
        }
        __syncthreads();   // staged data visible

        float ee_val = Es[(c << 5) + n];

        f32x16 acc;
#pragma unroll
        for (int r = 0; r < 16; ++r) acc[r] = ee_val;   // d = ee + x·(-2e)

#pragma unroll
        for (int s = 0; s < 8; ++s) {
            U8 bh;
            bh.u = Bs[s * 64 + lane];
            acc = __builtin_amdgcn_mfma_f32_32x32x16_f16(xh[s], bh.h, acc, 0, 0, 0);
            acc = __builtin_amdgcn_mfma_f32_32x32x16_f16(xl[s], bh.h, acc, 0, 0, 0);
        }

#pragma unroll
        for (int r = 0; r < 16; ++r) {
            int p = (int)((__float_as_int(acc[r]) & 0xFFFFFFE0u) | (unsigned)c);
            int old = bestv[r];
            bestv[r] = min(old, p);
            best2[r] = min(best2[r], max(old, p));
        }
    }

    // unpack to (dist, dist2, full index) for the cross-lane merge
    float fv[16], f2[16];
    int   bi[16];
#pragma unroll
    for (int r = 0; r < 16; ++r) {
        fv[r] = __int_as_float((int)(bestv[r] & 0xFFFFFFE0u));
        f2[r] = __int_as_float((int)(best2[r] & 0xFFFFFFE0u));
        bi[r] = ((bestv[r] & 31) << 5) | n;
    }

    // cross-lane (32 columns) top-2 merge via butterfly
#pragma unroll
    for (int m = 1; m <= 16; m <<= 1) {
#pragma unroll
        for (int r = 0; r < 16; ++r) {
            float ov = __shfl_xor(fv[r], m, 64);
            float o2 = __shfl_xor(f2[r], m, 64);
            int   oi = __shfl_xor(bi[r], m, 64);
            float hi = fmaxf(fv[r], ov);
            f2[r] = fminf(fminf(f2[r], o2), hi);
            bool take = (ov < fv[r]) || (ov == fv[r] && oi < bi[r]);
            fv[r] = take ? ov : fv[r];
            bi[r] = take ? oi : bi[r];
        }
    }

    if (n == 0) {
#pragma unroll
        for (int r = 0; r < 16; ++r) {
            int row = row0 + wave * 32 + (r & 3) + 8 * (r >> 2) + 4 * h;
            ind_i[row] = bi[r];
            ind_f[row] = (float)bi[r];
            if (f2[r] - fv[r] < TAU) {
                int p = atomicAdd(wl_cnt, 1);
                if (p < NROWS) wl[p] = row;
            }
        }
    }
}

// ---------------- exact fp32 re-check for near-tie rows (fixes ind only) ----------------
__global__ __launch_bounds__(256) void recheck_kernel(
    const float* __restrict__ x, const float* __restrict__ embed,
    const float* __restrict__ enorm, const int* __restrict__ wl,
    const int* __restrict__ wl_cnt, int* __restrict__ ind_i, float* __restrict__ ind_f)
{
    __shared__ float xs[DIMD];
    __shared__ float rv[256];
    __shared__ int   ri[256];
    const int tid = threadIdx.x;
    int count = *wl_cnt;
    if (count > NROWS) count = NROWS;

    for (int i = blockIdx.x; i < count; i += gridDim.x) {
        const int row = wl[i];
        __syncthreads();
        if (tid < DIMD) xs[tid] = x[(size_t)row * DIMD + tid];
        __syncthreads();

        const float4* xs4 = (const float4*)xs;
        float xn = 0.f;
#pragma unroll 8
        for (int c = 0; c < 32; ++c) {
            float4 v = xs4[c];
            xn += v.x * v.x + v.y * v.y + v.z * v.z + v.w * v.w;
        }

        float bv = FLT_MAX; int bi = 0;
#pragma unroll
        for (int c = 0; c < 4; ++c) {
            int code = tid * 4 + c;
            const float4* er = (const float4*)(embed + (size_t)code * DIMD);
            float acc = 0.f;
#pragma unroll 8
            for (int kk = 0; kk < 32; ++kk) {
                float4 a = xs4[kk];
                float4 b = er[kk];
                acc += a.x * b.x + a.y * b.y + a.z * b.z + a.w * b.w;
            }
            float d = (xn - 2.0f * acc) + enorm[code];
            if (d < bv) { bv = d; bi = code; }
        }
        rv[tid] = bv; ri[tid] = bi;
        __syncthreads();
        for (int s = 128; s > 0; s >>= 1) {
            if (tid < s) {
                if (rv[tid + s] < rv[tid] || (rv[tid + s] == rv[tid] && ri[tid + s] < ri[tid])) {
                    rv[tid] = rv[tid + s]; ri[tid] = ri[tid + s];
                }
            }
            __syncthreads();
        }
        if (tid == 0) {
            int s_new = ri[0];
            if (s_new != ind_i[row]) {
                ind_i[row] = s_new;
                ind_f[row] = (float)s_new;
            }
        }
        __syncthreads();
    }
}

// ---------------- histogram of final code assignments (LDS-aggregated) ----------------
__global__ __launch_bounds__(256) void hist_kernel(
    const int* __restrict__ ind, int* __restrict__ counts)
{
    __shared__ int hcnt[KCODES];
    for (int i = threadIdx.x; i < KCODES; i += 256) hcnt[i] = 0;
    __syncthreads();
    const int base = blockIdx.x * 2048;
    for (int i = threadIdx.x; i < 2048; i += 256) atomicAdd(&hcnt[ind[base + i]], 1);
    __syncthreads();
    for (int i = threadIdx.x; i < KCODES; i += 256) {
        int v = hcnt[i];
        if (v) atomicAdd(&counts[i], v);
    }
}

// ---------------- fused: exclusive scan (cursor) + cluster EMA + smoothed ----------------
__global__ __launch_bounds__(1024) void scan_cluster_kernel(
    const int* __restrict__ counts, const float* __restrict__ cluster_size,
    int* __restrict__ cursor, float* __restrict__ out_cs, float* __restrict__ smoothed)
{
    __shared__ int   s[KCODES];
    __shared__ float rf[KCODES];
    const int t = threadIdx.x;
    int my = counts[t];
    s[t] = my;
    float cs = cluster_size[t] * 0.99f + (float)my * 0.01f;
    out_cs[t] = cs;
    rf[t] = cs;
    __syncthreads();
    for (int d = 1; d < KCODES; d <<= 1) {
        int v = (t >= d) ? s[t - d] : 0;
        __syncthreads();
        s[t] += v;
        __syncthreads();
    }
    cursor[t] = s[t] - my;
    for (int st = 512; st > 0; st >>= 1) {
        if (t < st) rf[t] += rf[t + st];
        __syncthreads();
    }
    float total = rf[0];
    smoothed[t] = (cs + 1e-6f) / (total + 1e-6f * (float)KCODES) * total;
}

// ---- build permutation (1 thread / row) + zero embed_sum ----
__global__ __launch_bounds__(256) void permbuild_kernel(
    const int* __restrict__ ind, int* __restrict__ cursor,
    int* __restrict__ perm, int* __restrict__ codes, uint4* __restrict__ embed_sum4)
{
    const int tid = threadIdx.x;
    // zero 128 uint4 of embed_sum per block (256 blocks x 128 = full 512 KB)
    if (tid < 128) {
        uint4 z = {0, 0, 0, 0};
        embed_sum4[blockIdx.x * 128 + tid] = z;
    }
    const int row = blockIdx.x * 256 + tid;
    const int k = ind[row];
    int pos = atomicAdd(&cursor[k], 1);
    perm[pos] = row;
    codes[pos] = k;
}

// ---- balanced chunked segmented sum (boundary atomics) + fused out_q gather ----
__global__ __launch_bounds__(256) void segsum_kernel(
    const float* __restrict__ x, const float* __restrict__ embed,
    const int* __restrict__ perm, const int* __restrict__ codes,
    float* __restrict__ embed_sum, float* __restrict__ out_q)
{
    const int g = (blockIdx.x * 256 + threadIdx.x) >> 5;   // group id, 0..4095
    const int c = threadIdx.x & 31;                        // lane owns cols 4c..4c+3
    const int base = g * SEG_R;

    float4 acc = {0.f, 0.f, 0.f, 0.f};
    int curk = codes[base];
#pragma unroll
    for (int j = 0; j < SEG_R; ++j) {
        int r = perm[base + j];
        int k = codes[base + j];
        float4 v = *(const float4*)(x + (size_t)r * DIMD + c * 4);
        // fused quantize output: out_q[r] = embed[k]  (embed L2-resident)
        float4 e = *(const float4*)(embed + (size_t)k * DIMD + c * 4);
        *(float4*)(out_q + (size_t)r * DIMD + c * 4) = e;
        if (k != curk) {
            float* dst = embed_sum + (size_t)curk * DIMD + c * 4;
            atomicAdd(dst + 0, acc.x);
            atomicAdd(dst + 1, acc.y);
            atomicAdd(dst + 2, acc.z);
            atomicAdd(dst + 3, acc.w);
            acc = v;
            curk = k;
        } else {
            acc.x += v.x; acc.y += v.y; acc.z += v.z; acc.w += v.w;
        }
    }
    float* dst = embed_sum + (size_t)curk * DIMD + c * 4;
    atomicAdd(dst + 0, acc.x);
    atomicAdd(dst + 1, acc.y);
    atomicAdd(dst + 2, acc.z);
    atomicAdd(dst + 3, acc.w);
}

// ---------------- embed_avg EMA + embed_new ----------------
__global__ void embed_kernel(
    const float* __restrict__ embed_avg, const float* __restrict__ embed_sum,
    const float* __restrict__ smoothed, float* __restrict__ out_ea,
    float* __restrict__ out_en)
{
    int i = blockIdx.x * blockDim.x + threadIdx.x;
    if (i < KCODES * DIMD) {
        float ea = embed_avg[i] * 0.99f + embed_sum[i] * 0.01f;
        out_ea[i] = ea;
        out_en[i] = ea / smoothed[i >> 7];
    }
}

extern "C" void kernel_launch(void* const* d_in, const int* in_sizes, int n_in,
                              void* d_out, int out_size, void* d_ws, size_t ws_size,
                              hipStream_t stream) {
    const float* x            = (const float*)d_in[0];
    const float* embed        = (const float*)d_in[1];
    const float* cluster_size = (const float*)d_in[2];
    const float* embed_avg    = (const float*)d_in[3];

    float* out     = (float*)d_out;
    float* out_q   = out;                       // [65536*128]
    float* out_ind = out + 8388608;             // [65536]
    float* out_cs  = out + 8454144;             // [1024]
    float* out_ea  = out + 8455168;             // [1024*128]
    float* out_en  = out + 8586240;             // [1024*128]

    char* ws = (char*)d_ws;
    int*   ind_i     = (int*)(ws + 0);          // 256 KB
    float* enorm     = (float*)(ws + 262144);   // 4 KB
    int*   countsI   = (int*)(ws + 266240);     // 4 KB  \ zeroed by pre_kernel blk 68
    int*   wl_cnt    = (int*)(ws + 270336);     // 4 KB  /
    int*   cursor    = (int*)(ws + 274432);     // 4 KB
    float* smoothed  = (float*)(ws + 278528);   // 4 KB
    int*   perm      = (int*)(ws + 286720);     // 256 KB
    int*   wl        = (int*)(ws + 548864);     // 256 KB (dead after recheck)
    int*   codes     = (int*)(ws + 548864);     // 256 KB — ALIASES wl (disjoint lifetime)
    uint4* ehg       = (uint4*)(ws + 811008);   // 256 KB f16 (-2e) codebook (dead after argmin)
    float* embed_sum = (float*)(ws + 811008);   // 512 KB — ALIASES ehg (disjoint lifetime;
                                                //          zeroed inside permbuild)

    pre_kernel<<<69, 256, 0, stream>>>(embed, ehg, enorm, (uint4*)countsI);
    argmin_mfma<<<NROWS / 128, 256, 0, stream>>>(
        x, ehg, enorm, ind_i, out_ind, wl, wl_cnt);
    recheck_kernel<<<512, 256, 0, stream>>>(
        x, embed, enorm, wl, wl_cnt, ind_i, out_ind);
    hist_kernel<<<32, 256, 0, stream>>>(ind_i, countsI);
    scan_cluster_kernel<<<1, 1024, 0, stream>>>(countsI, cluster_size, cursor, out_cs, smoothed);
    permbuild_kernel<<<NROWS / 256, 256, 0, stream>>>(
        ind_i, cursor, perm, codes, (uint4*)embed_sum);
    segsum_kernel<<<(NROWS / SEG_R) * 32 / 256, 256, 0, stream>>>(
        x, embed, perm, codes, embed_sum, out_q);
    embed_kernel<<<(KCODES * DIMD + 255) / 256, 256, 0, stream>>>(
        embed_avg, embed_sum, smoothed, out_ea, out_en);
}

// Round 6
// 259.804 us; speedup vs baseline: 1.0220x; 1.0220x over previous
//
#include <hip/hip_runtime.h>
#include <hip/hip_fp16.h>
#include <float.h>

#define DIMD   128
#define KCODES 1024
#define NROWS  65536
#define TAU    0.03f
#define SEG_R  16    // rows per segsum group

typedef __attribute__((ext_vector_type(8)))  _Float16 half8;
typedef __attribute__((ext_vector_type(16))) float f32x16;

union U8 { uint4 u; half8 h; };

__device__ __forceinline__ unsigned packh2(float a, float b) {
    __half2 t = __floats2half2_rn(a, b);
    return *(unsigned*)&t;
}

// ---- fused: preconvert codebook f16-hi (blocks 0..63) + enorm (64..67) + zero counts (68) ----
__global__ __launch_bounds__(256) void pre_kernel(
    const float* __restrict__ embed, uint4* __restrict__ ehg,
    float* __restrict__ enorm, uint4* __restrict__ zero_region)
{
    if (blockIdx.x < 64) {
        int t = blockIdx.x * 256 + threadIdx.x;     // 0..16383
        int chunk = t >> 9;
        int s = (t >> 6) & 7;
        int L = t & 63;
        const float* src = embed + ((size_t)(chunk * 32 + (L & 31)) * DIMD) + s * 16 + (L >> 5) * 8;
        float4 a = *(const float4*)src;
        float4 b = *(const float4*)(src + 4);
        float f[8] = {a.x, a.y, a.z, a.w, b.x, b.y, b.z, b.w};
        uint4 H;
        unsigned* hw = (unsigned*)&H;
#pragma unroll
        for (int j = 0; j < 4; ++j) hw[j] = packh2(f[2 * j], f[2 * j + 1]);
        ehg[t] = H;
    } else if (blockIdx.x < 68) {
        int k = (blockIdx.x - 64) * 256 + threadIdx.x;
        const float4* e = (const float4*)(embed + (size_t)k * DIMD);
        float s = 0.f;
#pragma unroll
        for (int c = 0; c < DIMD / 4; ++c) {
            float4 v = e[c];
            s += v.x * v.x + v.y * v.y + v.z * v.z + v.w * v.w;
        }
        enorm[k] = s;
    } else {
        uint4 z = {0, 0, 0, 0};
        zero_region[threadIdx.x] = z;
        zero_region[threadIdx.x + 256] = z;
    }
}

// ---------------- fused MFMA distance (f16 2-term: (xh+xl)·eh) + argmin (top-2) ----------------
// R6 structural change (the ONLY delta vs the proven 58.6 µs R0 kernel): NO LDS staging.
// B-fragments are read straight from L2 — ehg is 256 KB, resident in each XCD's 4 MB L2;
// bp[s*64+lane] is the same coalesced 1KB/instr pattern as the old ds_read. This deletes
// both per-chunk __syncthreads and the stage->drain->compute serialization that R1/R3/R4
// failed to pipeline (each wave is now an independent dataflow; latency hides across the
// 8 resident waves/CU). L2 traffic 512 MB ≈ 15 µs at 34.5 TB/s; MFMA floor 13.7 µs.
// Session ledger (do not revisit):
//  - R1/R4: global_load_lds dbuf, either order -> 77-79 µs + 6 MB spill signature.
//  - R2: launch_bounds(256,4) -> 128-unified-reg cap, 1.5 GB scratch, 533 µs.
//  - R3: K-split for occupancy -> occupancy stayed ~20%, staging doubled, 74 µs.
//  - R5: "VALU wins" retrofit (packed-int top-2/acc=ee/Es-LDS) on R0 structure ->
//    same 6 MB spill signature, 81 µs. R0's epilogue/regalloc is fragile: keep it VERBATIM.
// __launch_bounds__(256,2): VGPR cap 256 — kernel needs ~130. Do not raise the hint.
__global__ __launch_bounds__(256, 2) void argmin_mfma(
    const float* __restrict__ x, const uint4* __restrict__ ehg,
    const float* __restrict__ enorm,
    int* __restrict__ ind_i, float* __restrict__ ind_f,
    int* __restrict__ wl, int* __restrict__ wl_cnt)
{
    const int tid  = threadIdx.x;
    const int wave = tid >> 6;
    const int lane = tid & 63;
    const int n    = lane & 31;
    const int h    = lane >> 5;
    const int row0 = blockIdx.x * 128;
    const int rowA = row0 + wave * 32 + n;

    // A fragments: x split into f16 hi/lo, held in regs for all 8 k-steps
    uint4 xh[8], xl[8];
    const float* xrow = x + (size_t)rowA * DIMD + h * 8;
#pragma unroll
    for (int s = 0; s < 8; ++s) {
        float4 a = *(const float4*)(xrow + s * 16);
        float4 b = *(const float4*)(xrow + s * 16 + 4);
        float f[8] = {a.x, a.y, a.z, a.w, b.x, b.y, b.z, b.w};
        unsigned* ph = (unsigned*)&xh[s];
        unsigned* pl = (unsigned*)&xl[s];
#pragma unroll
        for (int j = 0; j < 4; ++j) {
            float u0 = f[2 * j], u1 = f[2 * j + 1];
            __half2 hh = __floats2half2_rn(u0, u1);
            ph[j] = *(unsigned*)&hh;
            float2 back = __half22float2(hh);
            __half2 ll = __floats2half2_rn(u0 - back.x, u1 - back.y);
            pl[j] = *(unsigned*)&ll;
        }
    }

    float bestv[16], best2[16];
    int   besti[16];
#pragma unroll
    for (int r = 0; r < 16; ++r) { bestv[r] = FLT_MAX; best2[r] = FLT_MAX; besti[r] = 0; }

    for (int chunk = 0; chunk < KCODES / 32; ++chunk) {
        const uint4* bp = ehg + (size_t)chunk * 512;   // this chunk's B frags (L2-resident)
        float ee_val = enorm[chunk * 32 + n];

        f32x16 acc;
#pragma unroll
        for (int r = 0; r < 16; ++r) acc[r] = 0.f;

#pragma unroll
        for (int s = 0; s < 8; ++s) {
            U8 ah, al, bh;
            ah.u = xh[s]; al.u = xl[s];
            bh.u = bp[s * 64 + lane];                  // coalesced 16B/lane from L2
            acc = __builtin_amdgcn_mfma_f32_32x32x16_f16(ah.h, bh.h, acc, 0, 0, 0);
            acc = __builtin_amdgcn_mfma_f32_32x32x16_f16(al.h, bh.h, acc, 0, 0, 0);
        }

        const int nglob = chunk * 32 + n;
#pragma unroll
        for (int r = 0; r < 16; ++r) {
            float d = fmaf(-2.f, acc[r], ee_val);
            bool c1 = d < bestv[r];
            float t = c1 ? bestv[r] : d;
            best2[r] = fminf(best2[r], t);
            besti[r] = c1 ? nglob : besti[r];
            bestv[r] = fminf(bestv[r], d);
        }
    }

    // cross-lane (32 columns) top-2 merge via butterfly
#pragma unroll
    for (int m = 1; m <= 16; m <<= 1) {
#pragma unroll
        for (int r = 0; r < 16; ++r) {
            float ov = __shfl_xor(bestv[r], m, 64);
            float o2 = __shfl_xor(best2[r], m, 64);
            int   oi = __shfl_xor(besti[r], m, 64);
            float hi = fmaxf(bestv[r], ov);
            best2[r] = fminf(fminf(best2[r], o2), hi);
            bool take = (ov < bestv[r]) || (ov == bestv[r] && oi < besti[r]);
            bestv[r] = take ? ov : bestv[r];
            besti[r] = take ? oi : besti[r];
        }
    }

    if (n == 0) {
#pragma unroll
        for (int r = 0; r < 16; ++r) {
            int row = row0 + wave * 32 + (r & 3) + 8 * (r >> 2) + 4 * h;
            ind_i[row] = besti[r];
            ind_f[row] = (float)besti[r];
            if (best2[r] - bestv[r] < TAU) {
                int p = atomicAdd(wl_cnt, 1);
                if (p < NROWS) wl[p] = row;
            }
        }
    }
}

// ---------------- exact fp32 re-check for near-tie rows (fixes ind only) ----------------
__global__ __launch_bounds__(256) void recheck_kernel(
    const float* __restrict__ x, const float* __restrict__ embed,
    const float* __restrict__ enorm, const int* __restrict__ wl,
    const int* __restrict__ wl_cnt, int* __restrict__ ind_i, float* __restrict__ ind_f)
{
    __shared__ float xs[DIMD];
    __shared__ float rv[256];
    __shared__ int   ri[256];
    const int tid = threadIdx.x;
    int count = *wl_cnt;
    if (count > NROWS) count = NROWS;

    for (int i = blockIdx.x; i < count; i += gridDim.x) {
        const int row = wl[i];
        __syncthreads();
        if (tid < DIMD) xs[tid] = x[(size_t)row * DIMD + tid];
        __syncthreads();

        const float4* xs4 = (const float4*)xs;
        float xn = 0.f;
#pragma unroll 8
        for (int c = 0; c < 32; ++c) {
            float4 v = xs4[c];
            xn += v.x * v.x + v.y * v.y + v.z * v.z + v.w * v.w;
        }

        float bv = FLT_MAX; int bi = 0;
#pragma unroll
        for (int c = 0; c < 4; ++c) {
            int code = tid * 4 + c;
            const float4* er = (const float4*)(embed + (size_t)code * DIMD);
            float acc = 0.f;
#pragma unroll 8
            for (int kk = 0; kk < 32; ++kk) {
                float4 a = xs4[kk];
                float4 b = er[kk];
                acc += a.x * b.x + a.y * b.y + a.z * b.z + a.w * b.w;
            }
            float d = (xn - 2.0f * acc) + enorm[code];
            if (d < bv) { bv = d; bi = code; }
        }
        rv[tid] = bv; ri[tid] = bi;
        __syncthreads();
        for (int s = 128; s > 0; s >>= 1) {
            if (tid < s) {
                if (rv[tid + s] < rv[tid] || (rv[tid + s] == rv[tid] && ri[tid + s] < ri[tid])) {
                    rv[tid] = rv[tid + s]; ri[tid] = ri[tid + s];
                }
            }
            __syncthreads();
        }
        if (tid == 0) {
            int s_new = ri[0];
            if (s_new != ind_i[row]) {
                ind_i[row] = s_new;
                ind_f[row] = (float)s_new;
            }
        }
        __syncthreads();
    }
}

// ---------------- histogram of final code assignments (LDS-aggregated) ----------------
__global__ __launch_bounds__(256) void hist_kernel(
    const int* __restrict__ ind, int* __restrict__ counts)
{
    __shared__ int hcnt[KCODES];
    for (int i = threadIdx.x; i < KCODES; i += 256) hcnt[i] = 0;
    __syncthreads();
    const int base = blockIdx.x * 2048;
    for (int i = threadIdx.x; i < 2048; i += 256) atomicAdd(&hcnt[ind[base + i]], 1);
    __syncthreads();
    for (int i = threadIdx.x; i < KCODES; i += 256) {
        int v = hcnt[i];
        if (v) atomicAdd(&counts[i], v);
    }
}

// ---------------- fused: exclusive scan (cursor) + cluster EMA + smoothed ----------------
__global__ __launch_bounds__(1024) void scan_cluster_kernel(
    const int* __restrict__ counts, const float* __restrict__ cluster_size,
    int* __restrict__ cursor, float* __restrict__ out_cs, float* __restrict__ smoothed)
{
    __shared__ int   s[KCODES];
    __shared__ float rf[KCODES];
    const int t = threadIdx.x;
    int my = counts[t];
    s[t] = my;
    float cs = cluster_size[t] * 0.99f + (float)my * 0.01f;
    out_cs[t] = cs;
    rf[t] = cs;
    __syncthreads();
    for (int d = 1; d < KCODES; d <<= 1) {
        int v = (t >= d) ? s[t - d] : 0;
        __syncthreads();
        s[t] += v;
        __syncthreads();
    }
    cursor[t] = s[t] - my;
    for (int st = 512; st > 0; st >>= 1) {
        if (t < st) rf[t] += rf[t + st];
        __syncthreads();
    }
    float total = rf[0];
    smoothed[t] = (cs + 1e-6f) / (total + 1e-6f * (float)KCODES) * total;
}

// ---- build permutation (1 thread / row) + zero embed_sum ----
__global__ __launch_bounds__(256) void permbuild_kernel(
    const int* __restrict__ ind, int* __restrict__ cursor,
    int* __restrict__ perm, int* __restrict__ codes, uint4* __restrict__ embed_sum4)
{
    const int tid = threadIdx.x;
    // zero 128 uint4 of embed_sum per block (256 blocks x 128 = full 512 KB)
    if (tid < 128) {
        uint4 z = {0, 0, 0, 0};
        embed_sum4[blockIdx.x * 128 + tid] = z;
    }
    const int row = blockIdx.x * 256 + tid;
    const int k = ind[row];
    int pos = atomicAdd(&cursor[k], 1);
    perm[pos] = row;
    codes[pos] = k;
}

// ---- balanced chunked segmented sum (boundary atomics) + fused out_q gather ----
__global__ __launch_bounds__(256) void segsum_kernel(
    const float* __restrict__ x, const float* __restrict__ embed,
    const int* __restrict__ perm, const int* __restrict__ codes,
    float* __restrict__ embed_sum, float* __restrict__ out_q)
{
    const int g = (blockIdx.x * 256 + threadIdx.x) >> 5;   // group id, 0..4095
    const int c = threadIdx.x & 31;                        // lane owns cols 4c..4c+3
    const int base = g * SEG_R;

    float4 acc = {0.f, 0.f, 0.f, 0.f};
    int curk = codes[base];
#pragma unroll
    for (int j = 0; j < SEG_R; ++j) {
        int r = perm[base + j];
        int k = codes[base + j];
        float4 v = *(const float4*)(x + (size_t)r * DIMD + c * 4);
        // fused quantize output: out_q[r] = embed[k]  (embed L2-resident)
        float4 e = *(const float4*)(embed + (size_t)k * DIMD + c * 4);
        *(float4*)(out_q + (size_t)r * DIMD + c * 4) = e;
        if (k != curk) {
            float* dst = embed_sum + (size_t)curk * DIMD + c * 4;
            atomicAdd(dst + 0, acc.x);
            atomicAdd(dst + 1, acc.y);
            atomicAdd(dst + 2, acc.z);
            atomicAdd(dst + 3, acc.w);
            acc = v;
            curk = k;
        } else {
            acc.x += v.x; acc.y += v.y; acc.z += v.z; acc.w += v.w;
        }
    }
    float* dst = embed_sum + (size_t)curk * DIMD + c * 4;
    atomicAdd(dst + 0, acc.x);
    atomicAdd(dst + 1, acc.y);
    atomicAdd(dst + 2, acc.z);
    atomicAdd(dst + 3, acc.w);
}

// ---------------- embed_avg EMA + embed_new ----------------
__global__ void embed_kernel(
    const float* __restrict__ embed_avg, const float* __restrict__ embed_sum,
    const float* __restrict__ smoothed, float* __restrict__ out_ea,
    float* __restrict__ out_en)
{
    int i = blockIdx.x * blockDim.x + threadIdx.x;
    if (i < KCODES * DIMD) {
        float ea = embed_avg[i] * 0.99f + embed_sum[i] * 0.01f;
        out_ea[i] = ea;
        out_en[i] = ea / smoothed[i >> 7];
    }
}

extern "C" void kernel_launch(void* const* d_in, const int* in_sizes, int n_in,
                              void* d_out, int out_size, void* d_ws, size_t ws_size,
                              hipStream_t stream) {
    const float* x            = (const float*)d_in[0];
    const float* embed        = (const float*)d_in[1];
    const float* cluster_size = (const float*)d_in[2];
    const float* embed_avg    = (const float*)d_in[3];

    float* out     = (float*)d_out;
    float* out_q   = out;                       // [65536*128]
    float* out_ind = out + 8388608;             // [65536]
    float* out_cs  = out + 8454144;             // [1024]
    float* out_ea  = out + 8455168;             // [1024*128]
    float* out_en  = out + 8586240;             // [1024*128]

    char* ws = (char*)d_ws;
    int*   ind_i     = (int*)(ws + 0);          // 256 KB
    float* enorm     = (float*)(ws + 262144);   // 4 KB
    int*   countsI   = (int*)(ws + 266240);     // 4 KB  \ zeroed by pre_kernel blk 68
    int*   wl_cnt    = (int*)(ws + 270336);     // 4 KB  /
    int*   cursor    = (int*)(ws + 274432);     // 4 KB
    float* smoothed  = (float*)(ws + 278528);   // 4 KB
    int*   perm      = (int*)(ws + 286720);     // 256 KB
    int*   wl        = (int*)(ws + 548864);     // 256 KB (dead after recheck)
    int*   codes     = (int*)(ws + 548864);     // 256 KB — ALIASES wl (disjoint lifetime)
    uint4* ehg       = (uint4*)(ws + 811008);   // 256 KB f16-hi codebook (dead after argmin)
    float* embed_sum = (float*)(ws + 811008);   // 512 KB — ALIASES ehg (disjoint lifetime;
                                                //          zeroed inside permbuild)

    pre_kernel<<<69, 256, 0, stream>>>(embed, ehg, enorm, (uint4*)countsI);
    argmin_mfma<<<NROWS / 128, 256, 0, stream>>>(
        x, ehg, enorm, ind_i, out_ind, wl, wl_cnt);
    recheck_kernel<<<512, 256, 0, stream>>>(
        x, embed, enorm, wl, wl_cnt, ind_i, out_ind);
    hist_kernel<<<32, 256, 0, stream>>>(ind_i, countsI);
    scan_cluster_kernel<<<1, 1024, 0, stream>>>(countsI, cluster_size, cursor, out_cs, smoothed);
    permbuild_kernel<<<NROWS / 256, 256, 0, stream>>>(
        ind_i, cursor, perm, codes, (uint4*)embed_sum);
    segsum_kernel<<<(NROWS / SEG_R) * 32 / 256, 256, 0, stream>>>(
        x, embed, perm, codes, embed_sum, out_q);
    embed_kernel<<<(KCODES * DIMD + 255) / 256, 256, 0, stream>>>(
        embed_avg, embed_sum, smoothed, out_ea, out_en);
}

// Round 7
// 248.387 us; speedup vs baseline: 1.0690x; 1.0460x over previous
//
#include <hip/hip_runtime.h>
#include <hip/hip_fp16.h>
#include <float.h>

#define DIMD   128
#define KCODES 1024
#define NROWS  65536
#define TAU    0.03f
#define SEG_R  16    // rows per segsum group

typedef __attribute__((ext_vector_type(8)))  _Float16 half8;
typedef __attribute__((ext_vector_type(16))) float f32x16;

union U8 { uint4 u; half8 h; };

__device__ __forceinline__ unsigned packh2(float a, float b) {
    __half2 t = __floats2half2_rn(a, b);
    return *(unsigned*)&t;
}

// ---- fused: preconvert codebook f16-hi (blocks 0..63) + enorm (64..67) + zero counts (68) ----
__global__ __launch_bounds__(256) void pre_kernel(
    const float* __restrict__ embed, uint4* __restrict__ ehg,
    float* __restrict__ enorm, uint4* __restrict__ zero_region)
{
    if (blockIdx.x < 64) {
        int t = blockIdx.x * 256 + threadIdx.x;     // 0..16383
        int chunk = t >> 9;
        int s = (t >> 6) & 7;
        int L = t & 63;
        const float* src = embed + ((size_t)(chunk * 32 + (L & 31)) * DIMD) + s * 16 + (L >> 5) * 8;
        float4 a = *(const float4*)src;
        float4 b = *(const float4*)(src + 4);
        float f[8] = {a.x, a.y, a.z, a.w, b.x, b.y, b.z, b.w};
        uint4 H;
        unsigned* hw = (unsigned*)&H;
#pragma unroll
        for (int j = 0; j < 4; ++j) hw[j] = packh2(f[2 * j], f[2 * j + 1]);
        ehg[t] = H;
    } else if (blockIdx.x < 68) {
        int k = (blockIdx.x - 64) * 256 + threadIdx.x;
        const float4* e = (const float4*)(embed + (size_t)k * DIMD);
        float s = 0.f;
#pragma unroll
        for (int c = 0; c < DIMD / 4; ++c) {
            float4 v = e[c];
            s += v.x * v.x + v.y * v.y + v.z * v.z + v.w * v.w;
        }
        enorm[k] = s;
    } else {
        uint4 z = {0, 0, 0, 0};
        zero_region[threadIdx.x] = z;
        zero_region[threadIdx.x + 256] = z;
    }
}

// ---------------- fused MFMA distance (f16 2-term: (xh+xl)·eh) + argmin (top-2) ----------------
// R7 change vs the proven 58.6 µs R0 kernel: 2 CHUNKS PER BARRIER PAIR (Bs 8KB->16KB,
// stage 4 lines/thread, inner body repeated twice per staging event). Barrier pairs
// 32 -> 16; staged bytes / MFMA / top-2 work unchanged; inner body kept bit-for-bit R0.
// Mechanism: per-SIMD cost ≈ 4400 cyc/chunk at R0, compute only ~1/3 — the rest is
// per-chunk fixed cost (stage L2 latency + 2 barrier convoys). Halve its count.
// Session ledger (do not revisit):
//  - R1/R4: global_load_lds dbuf, either order -> 77-79 µs + 6 MB spill signature.
//  - R2: launch_bounds(256,4) -> 128-unified-reg cap, 1.5 GB scratch, 533 µs.
//  - R3: K-split for occupancy -> occupancy stayed ~20%, staging doubled, 74 µs.
//  - R5: "VALU wins" retrofit (packed-int top-2/acc=ee/Es-LDS) -> 6 MB spill, 81 µs.
//    R0's epilogue/regalloc is fragile: keep the inner body VERBATIM.
//  - R6: no-LDS (B direct from L2) -> 74 µs, no spill: exposed L2 latency at 2 waves/SIMD.
// __launch_bounds__(256,2): VGPR cap 256 — kernel needs ~130. Do not raise the hint.
__global__ __launch_bounds__(256, 2) void argmin_mfma(
    const float* __restrict__ x, const uint4* __restrict__ ehg,
    const float* __restrict__ enorm,
    int* __restrict__ ind_i, float* __restrict__ ind_f,
    int* __restrict__ wl, int* __restrict__ wl_cnt)
{
    __shared__ uint4 Bs[1024];    // TWO chunks of eh f16 frags (16 KB)

    const int tid  = threadIdx.x;
    const int wave = tid >> 6;
    const int lane = tid & 63;
    const int n    = lane & 31;
    const int h    = lane >> 5;
    const int row0 = blockIdx.x * 128;
    const int rowA = row0 + wave * 32 + n;

    // A fragments: x split into f16 hi/lo, held in regs for all 8 k-steps
    uint4 xh[8], xl[8];
    const float* xrow = x + (size_t)rowA * DIMD + h * 8;
#pragma unroll
    for (int s = 0; s < 8; ++s) {
        float4 a = *(const float4*)(xrow + s * 16);
        float4 b = *(const float4*)(xrow + s * 16 + 4);
        float f[8] = {a.x, a.y, a.z, a.w, b.x, b.y, b.z, b.w};
        unsigned* ph = (unsigned*)&xh[s];
        unsigned* pl = (unsigned*)&xl[s];
#pragma unroll
        for (int j = 0; j < 4; ++j) {
            float u0 = f[2 * j], u1 = f[2 * j + 1];
            __half2 hh = __floats2half2_rn(u0, u1);
            ph[j] = *(unsigned*)&hh;
            float2 back = __half22float2(hh);
            __half2 ll = __floats2half2_rn(u0 - back.x, u1 - back.y);
            pl[j] = *(unsigned*)&ll;
        }
    }

    float bestv[16], best2[16];
    int   besti[16];
#pragma unroll
    for (int r = 0; r < 16; ++r) { bestv[r] = FLT_MAX; best2[r] = FLT_MAX; besti[r] = 0; }

    for (int cc = 0; cc < KCODES / 64; ++cc) {
        __syncthreads();   // previous pair's Bs reads done
        {
            const uint4* sh = ehg + (size_t)cc * 1024;
            Bs[tid]       = sh[tid];
            Bs[tid + 256] = sh[tid + 256];
            Bs[tid + 512] = sh[tid + 512];
            Bs[tid + 768] = sh[tid + 768];
        }
        __syncthreads();   // staged data visible

#pragma unroll
        for (int half = 0; half < 2; ++half) {
            const int chunk = cc * 2 + half;
            float ee_val = enorm[chunk * 32 + n];

            f32x16 acc;
#pragma unroll
            for (int r = 0; r < 16; ++r) acc[r] = 0.f;

#pragma unroll
            for (int s = 0; s < 8; ++s) {
                U8 ah, al, bh;
                ah.u = xh[s]; al.u = xl[s];
                bh.u = Bs[half * 512 + s * 64 + lane];
                acc = __builtin_amdgcn_mfma_f32_32x32x16_f16(ah.h, bh.h, acc, 0, 0, 0);
                acc = __builtin_amdgcn_mfma_f32_32x32x16_f16(al.h, bh.h, acc, 0, 0, 0);
            }

            const int nglob = chunk * 32 + n;
#pragma unroll
            for (int r = 0; r < 16; ++r) {
                float d = fmaf(-2.f, acc[r], ee_val);
                bool c1 = d < bestv[r];
                float t = c1 ? bestv[r] : d;
                best2[r] = fminf(best2[r], t);
                besti[r] = c1 ? nglob : besti[r];
                bestv[r] = fminf(bestv[r], d);
            }
        }
    }

    // cross-lane (32 columns) top-2 merge via butterfly
#pragma unroll
    for (int m = 1; m <= 16; m <<= 1) {
#pragma unroll
        for (int r = 0; r < 16; ++r) {
            float ov = __shfl_xor(bestv[r], m, 64);
            float o2 = __shfl_xor(best2[r], m, 64);
            int   oi = __shfl_xor(besti[r], m, 64);
            float hi = fmaxf(bestv[r], ov);
            best2[r] = fminf(fminf(best2[r], o2), hi);
            bool take = (ov < bestv[r]) || (ov == bestv[r] && oi < besti[r]);
            bestv[r] = take ? ov : bestv[r];
            besti[r] = take ? oi : besti[r];
        }
    }

    if (n == 0) {
#pragma unroll
        for (int r = 0; r < 16; ++r) {
            int row = row0 + wave * 32 + (r & 3) + 8 * (r >> 2) + 4 * h;
            ind_i[row] = besti[r];
            ind_f[row] = (float)besti[r];
            if (best2[r] - bestv[r] < TAU) {
                int p = atomicAdd(wl_cnt, 1);
                if (p < NROWS) wl[p] = row;
            }
        }
    }
}

// ---------------- exact fp32 re-check for near-tie rows (fixes ind only) ----------------
__global__ __launch_bounds__(256) void recheck_kernel(
    const float* __restrict__ x, const float* __restrict__ embed,
    const float* __restrict__ enorm, const int* __restrict__ wl,
    const int* __restrict__ wl_cnt, int* __restrict__ ind_i, float* __restrict__ ind_f)
{
    __shared__ float xs[DIMD];
    __shared__ float rv[256];
    __shared__ int   ri[256];
    const int tid = threadIdx.x;
    int count = *wl_cnt;
    if (count > NROWS) count = NROWS;

    for (int i = blockIdx.x; i < count; i += gridDim.x) {
        const int row = wl[i];
        __syncthreads();
        if (tid < DIMD) xs[tid] = x[(size_t)row * DIMD + tid];
        __syncthreads();

        const float4* xs4 = (const float4*)xs;
        float xn = 0.f;
#pragma unroll 8
        for (int c = 0; c < 32; ++c) {
            float4 v = xs4[c];
            xn += v.x * v.x + v.y * v.y + v.z * v.z + v.w * v.w;
        }

        float bv = FLT_MAX; int bi = 0;
#pragma unroll
        for (int c = 0; c < 4; ++c) {
            int code = tid * 4 + c;
            const float4* er = (const float4*)(embed + (size_t)code * DIMD);
            float acc = 0.f;
#pragma unroll 8
            for (int kk = 0; kk < 32; ++kk) {
                float4 a = xs4[kk];
                float4 b = er[kk];
                acc += a.x * b.x + a.y * b.y + a.z * b.z + a.w * b.w;
            }
            float d = (xn - 2.0f * acc) + enorm[code];
            if (d < bv) { bv = d; bi = code; }
        }
        rv[tid] = bv; ri[tid] = bi;
        __syncthreads();
        for (int s = 128; s > 0; s >>= 1) {
            if (tid < s) {
                if (rv[tid + s] < rv[tid] || (rv[tid + s] == rv[tid] && ri[tid + s] < ri[tid])) {
                    rv[tid] = rv[tid + s]; ri[tid] = ri[tid + s];
                }
            }
            __syncthreads();
        }
        if (tid == 0) {
            int s_new = ri[0];
            if (s_new != ind_i[row]) {
                ind_i[row] = s_new;
                ind_f[row] = (float)s_new;
            }
        }
        __syncthreads();
    }
}

// ---------------- histogram of final code assignments (LDS-aggregated) ----------------
__global__ __launch_bounds__(256) void hist_kernel(
    const int* __restrict__ ind, int* __restrict__ counts)
{
    __shared__ int hcnt[KCODES];
    for (int i = threadIdx.x; i < KCODES; i += 256) hcnt[i] = 0;
    __syncthreads();
    const int base = blockIdx.x * 2048;
    for (int i = threadIdx.x; i < 2048; i += 256) atomicAdd(&hcnt[ind[base + i]], 1);
    __syncthreads();
    for (int i = threadIdx.x; i < KCODES; i += 256) {
        int v = hcnt[i];
        if (v) atomicAdd(&counts[i], v);
    }
}

// ---------------- fused: exclusive scan (cursor) + cluster EMA + smoothed ----------------
__global__ __launch_bounds__(1024) void scan_cluster_kernel(
    const int* __restrict__ counts, const float* __restrict__ cluster_size,
    int* __restrict__ cursor, float* __restrict__ out_cs, float* __restrict__ smoothed)
{
    __shared__ int   s[KCODES];
    __shared__ float rf[KCODES];
    const int t = threadIdx.x;
    int my = counts[t];
    s[t] = my;
    float cs = cluster_size[t] * 0.99f + (float)my * 0.01f;
    out_cs[t] = cs;
    rf[t] = cs;
    __syncthreads();
    for (int d = 1; d < KCODES; d <<= 1) {
        int v = (t >= d) ? s[t - d] : 0;
        __syncthreads();
        s[t] += v;
        __syncthreads();
    }
    cursor[t] = s[t] - my;
    for (int st = 512; st > 0; st >>= 1) {
        if (t < st) rf[t] += rf[t + st];
        __syncthreads();
    }
    float total = rf[0];
    smoothed[t] = (cs + 1e-6f) / (total + 1e-6f * (float)KCODES) * total;
}

// ---- build permutation (1 thread / row) + zero embed_sum ----
__global__ __launch_bounds__(256) void permbuild_kernel(
    const int* __restrict__ ind, int* __restrict__ cursor,
    int* __restrict__ perm, int* __restrict__ codes, uint4* __restrict__ embed_sum4)
{
    const int tid = threadIdx.x;
    // zero 128 uint4 of embed_sum per block (256 blocks x 128 = full 512 KB)
    if (tid < 128) {
        uint4 z = {0, 0, 0, 0};
        embed_sum4[blockIdx.x * 128 + tid] = z;
    }
    const int row = blockIdx.x * 256 + tid;
    const int k = ind[row];
    int pos = atomicAdd(&cursor[k], 1);
    perm[pos] = row;
    codes[pos] = k;
}

// ---- balanced chunked segmented sum (boundary atomics) + fused out_q gather ----
__global__ __launch_bounds__(256) void segsum_kernel(
    const float* __restrict__ x, const float* __restrict__ embed,
    const int* __restrict__ perm, const int* __restrict__ codes,
    float* __restrict__ embed_sum, float* __restrict__ out_q)
{
    const int g = (blockIdx.x * 256 + threadIdx.x) >> 5;   // group id, 0..4095
    const int c = threadIdx.x & 31;                        // lane owns cols 4c..4c+3
    const int base = g * SEG_R;

    float4 acc = {0.f, 0.f, 0.f, 0.f};
    int curk = codes[base];
#pragma unroll
    for (int j = 0; j < SEG_R; ++j) {
        int r = perm[base + j];
        int k = codes[base + j];
        float4 v = *(const float4*)(x + (size_t)r * DIMD + c * 4);
        // fused quantize output: out_q[r] = embed[k]  (embed L2-resident)
        float4 e = *(const float4*)(embed + (size_t)k * DIMD + c * 4);
        *(float4*)(out_q + (size_t)r * DIMD + c * 4) = e;
        if (k != curk) {
            float* dst = embed_sum + (size_t)curk * DIMD + c * 4;
            atomicAdd(dst + 0, acc.x);
            atomicAdd(dst + 1, acc.y);
            atomicAdd(dst + 2, acc.z);
            atomicAdd(dst + 3, acc.w);
            acc = v;
            curk = k;
        } else {
            acc.x += v.x; acc.y += v.y; acc.z += v.z; acc.w += v.w;
        }
    }
    float* dst = embed_sum + (size_t)curk * DIMD + c * 4;
    atomicAdd(dst + 0, acc.x);
    atomicAdd(dst + 1, acc.y);
    atomicAdd(dst + 2, acc.z);
    atomicAdd(dst + 3, acc.w);
}

// ---------------- embed_avg EMA + embed_new ----------------
__global__ void embed_kernel(
    const float* __restrict__ embed_avg, const float* __restrict__ embed_sum,
    const float* __restrict__ smoothed, float* __restrict__ out_ea,
    float* __restrict__ out_en)
{
    int i = blockIdx.x * blockDim.x + threadIdx.x;
    if (i < KCODES * DIMD) {
        float ea = embed_avg[i] * 0.99f + embed_sum[i] * 0.01f;
        out_ea[i] = ea;
        out_en[i] = ea / smoothed[i >> 7];
    }
}

extern "C" void kernel_launch(void* const* d_in, const int* in_sizes, int n_in,
                              void* d_out, int out_size, void* d_ws, size_t ws_size,
                              hipStream_t stream) {
    const float* x            = (const float*)d_in[0];
    const float* embed        = (const float*)d_in[1];
    const float* cluster_size = (const float*)d_in[2];
    const float* embed_avg    = (const float*)d_in[3];

    float* out     = (float*)d_out;
    float* out_q   = out;                       // [65536*128]
    float* out_ind = out + 8388608;             // [65536]
    float* out_cs  = out + 8454144;             // [1024]
    float* out_ea  = out + 8455168;             // [1024*128]
    float* out_en  = out + 8586240;             // [1024*128]

    char* ws = (char*)d_ws;
    int*   ind_i     = (int*)(ws + 0);          // 256 KB
    float* enorm     = (float*)(ws + 262144);   // 4 KB
    int*   countsI   = (int*)(ws + 266240);     // 4 KB  \ zeroed by pre_kernel blk 68
    int*   wl_cnt    = (int*)(ws + 270336);     // 4 KB  /
    int*   cursor    = (int*)(ws + 274432);     // 4 KB
    float* smoothed  = (float*)(ws + 278528);   // 4 KB
    int*   perm      = (int*)(ws + 286720);     // 256 KB
    int*   wl        = (int*)(ws + 548864);     // 256 KB (dead after recheck)
    int*   codes     = (int*)(ws + 548864);     // 256 KB — ALIASES wl (disjoint lifetime)
    uint4* ehg       = (uint4*)(ws + 811008);   // 256 KB f16-hi codebook (dead after argmin)
    float* embed_sum = (float*)(ws + 811008);   // 512 KB — ALIASES ehg (disjoint lifetime;
                                                //          zeroed inside permbuild)

    pre_kernel<<<69, 256, 0, stream>>>(embed, ehg, enorm, (uint4*)countsI);
    argmin_mfma<<<NROWS / 128, 256, 0, stream>>>(
        x, ehg, enorm, ind_i, out_ind, wl, wl_cnt);
    recheck_kernel<<<512, 256, 0, stream>>>(
        x, embed, enorm, wl, wl_cnt, ind_i, out_ind);
    hist_kernel<<<32, 256, 0, stream>>>(ind_i, countsI);
    scan_cluster_kernel<<<1, 1024, 0, stream>>>(countsI, cluster_size, cursor, out_cs, smoothed);
    permbuild_kernel<<<NROWS / 256, 256, 0, stream>>>(
        ind_i, cursor, perm, codes, (uint4*)embed_sum);
    segsum_kernel<<<(NROWS / SEG_R) * 32 / 256, 256, 0, stream>>>(
        x, embed, perm, codes, embed_sum, out_q);
    embed_kernel<<<(KCODES * DIMD + 255) / 256, 256, 0, stream>>>(
        embed_avg, embed_sum, smoothed, out_ea, out_en);
}